// Round 12
// baseline (171.381 us; speedup 1.0000x reference)
//
#include <hip/hip_runtime.h>
#include <math.h>

#define BB 32
#define TT 4096
#define DD 768
#define NH 4
#define RELW 32
#define NREL 65
#define HIDDEN 256
#define INPROJ 1792  // DD + NH*64 + DD

#define NCH 32
#define CROWS (TT / NCH)       // 128 rows per chunk (block)
#define TROWS 8                // rows per tile (2 per wave)
#define C4 (DD / 4)            // 192 float4 per row

#define WAITVM6() asm volatile("s_waitcnt vmcnt(6)" ::: "memory")
#define WAITVM0() asm volatile("s_waitcnt vmcnt(0)" ::: "memory")

__device__ __forceinline__ void gl_lds16(const float* g, float* l) {
    __builtin_amdgcn_global_load_lds(
        (const __attribute__((address_space(1))) float*)(uintptr_t)g,
        (__attribute__((address_space(3))) float*)(uintptr_t)l,
        16, 0, 0);
}

// ---- wave64 sum via DPP (VALU pipe) ----
template <int CTRL, int RMASK>
__device__ __forceinline__ float upd0(float x) {
    return __int_as_float(__builtin_amdgcn_update_dpp(
        0, __float_as_int(x), CTRL, RMASK, 0xf, true));
}
__device__ __forceinline__ float wave_sum64(float x) {
    x += upd0<0x111, 0xf>(x);   // row_shr:1
    x += upd0<0x112, 0xf>(x);   // row_shr:2
    x += upd0<0x114, 0xf>(x);   // row_shr:4
    x += upd0<0x118, 0xf>(x);   // row_shr:8
    x += upd0<0x142, 0xa>(x);   // row_bcast:15
    x += upd0<0x143, 0xc>(x);   // row_bcast:31 -> lane63 = total
    return __int_as_float(__builtin_amdgcn_readlane(__float_as_int(x), 63));
}

// ---------------- kA: qk = (h_i WQ WK)/8 only ----------------
__global__ __launch_bounds__(256) void kA(const float* __restrict__ H,
                                          const int* __restrict__ noun_pos,
                                          const float* __restrict__ WQ,
                                          const float* __restrict__ WK,
                                          float* __restrict__ qk_ws) {
    int b = blockIdx.x / NH, h = blockIdx.x % NH;
    __shared__ float hi_s[DD];
    __shared__ float qpart[4][64];
    __shared__ float q_s[64];
    int tn = noun_pos[b];
    const float* Hrow = H + ((size_t)b * TT + tn) * DD;
    for (int d = threadIdx.x; d < DD; d += 256) hi_s[d] = Hrow[d];
    __syncthreads();
    {   // q[k] = sum_d hi[d] * WQ[h,d,k] — 4-way d-split, coalesced across k
        int k = threadIdx.x & 63, ds = threadIdx.x >> 6;
        const float* wq = WQ + (size_t)h * DD * 64 + k;
        float acc = 0.f;
        #pragma unroll 8
        for (int d = ds * 192; d < ds * 192 + 192; ++d) acc += hi_s[d] * wq[(size_t)d * 64];
        qpart[ds][k] = acc;
    }
    __syncthreads();
    if (threadIdx.x < 64)
        q_s[threadIdx.x] = qpart[0][threadIdx.x] + qpart[1][threadIdx.x]
                         + qpart[2][threadIdx.x] + qpart[3][threadIdx.x];
    __syncthreads();
    for (int d = threadIdx.x; d < DD; d += 256) {
        const float* wk = WK + ((size_t)h * DD + d) * 64;
        float acc = 0.f;
        #pragma unroll
        for (int k = 0; k < 64; ++k) acc += q_s[k] * wk[k];
        qk_ws[((size_t)b * NH + h) * DD + d] = acc * 0.125f;  // 1/sqrt(64)
    }
}

// ---------------- kFlash: R9-exact — wave-independent, dbuf, no in-loop barriers ----------------
#define DOT(ACC, CV, QV) ACC += CV.x*QV.x + CV.y*QV.y + CV.z*QV.z + CV.w*QV.w

#define HUPD(M, L, S0, S1, B0, B1, B2)                                    \
  {                                                                        \
    float nm = fmaxf(M, fmaxf(S0, S1));                                    \
    if (nm > M + 8.0f) {                                                   \
      float sc = __expf(M - nm);                                           \
      L *= sc;                                                             \
      B0.x*=sc; B0.y*=sc; B0.z*=sc; B0.w*=sc;                              \
      B1.x*=sc; B1.y*=sc; B1.z*=sc; B1.w*=sc;                              \
      B2.x*=sc; B2.y*=sc; B2.z*=sc; B2.w*=sc;                              \
      M = nm;                                                              \
    }                                                                      \
    float p0 = __expf(S0 - M), p1 = __expf(S1 - M);                        \
    L += p0 + p1;                                                          \
    B0.x += p0*c0.x + p1*c3.x; B0.y += p0*c0.y + p1*c3.y;                  \
    B0.z += p0*c0.z + p1*c3.z; B0.w += p0*c0.w + p1*c3.w;                  \
    B1.x += p0*c1.x + p1*c4.x; B1.y += p0*c1.y + p1*c4.y;                  \
    B1.z += p0*c1.z + p1*c4.z; B1.w += p0*c1.w + p1*c4.w;                  \
    B2.x += p0*c2.x + p1*c5.x; B2.y += p0*c2.y + p1*c5.y;                  \
    B2.z += p0*c2.z + p1*c5.z; B2.w += p0*c2.w + p1*c5.w;                  \
  }

__global__ __launch_bounds__(256, 3) void kFlash(const float* __restrict__ H,
                                                 const int* __restrict__ mask,
                                                 const int* __restrict__ noun_pos,
                                                 const float* __restrict__ rel_bias,
                                                 const float* __restrict__ qk_ws,
                                                 float* __restrict__ macc,
                                                 float* __restrict__ ml) {
    const int b   = blockIdx.x / NCH;
    const int ch  = blockIdx.x % NCH;
    const int tid = threadIdx.x;
    const int wave = tid >> 6, lane = tid & 63;

    __shared__ float4 Hts[2][TROWS * C4];   // 48 KB: dbuf; reused as combine scratch
    __shared__ float4 rbL[CROWS];           // 2 KB
    __shared__ float mls[4][8];
    __shared__ int snl;

    const int t0 = ch * CROWS;
    const int tn = noun_pos[b];

    if (tid == 0) snl = 0;
    __syncthreads();
    if (tid < CROWS) {
        int t = t0 + tid;
        int dl = t - tn; dl = dl < -RELW ? -RELW : (dl > RELW ? RELW : dl);
        int mm = mask[(size_t)b * TT + t];
        float4 rv;
        if (mm) {
            rv.x = rel_bias[0 * NREL + dl + RELW];
            rv.y = rel_bias[1 * NREL + dl + RELW];
            rv.z = rel_bias[2 * NREL + dl + RELW];
            rv.w = rel_bias[3 * NREL + dl + RELW];
            atomicMax(&snl, tid + 1);
        } else {
            rv.x = rv.y = rv.z = rv.w = -2.0e9f;
        }
        rbL[tid] = rv;
    }

    float4 qr[NH][3];
    {
        const float4* qk4 = (const float4*)(qk_ws + (size_t)b * NH * DD);
        #pragma unroll
        for (int h = 0; h < NH; ++h)
            #pragma unroll
            for (int j = 0; j < 3; ++j)
                qr[h][j] = qk4[h * C4 + j * 64 + lane];
    }

    __syncthreads();
    const int NTE = (snl + TROWS - 1) / TROWS;

    if (NTE == 0) {
        float4 z = {0.f, 0.f, 0.f, 0.f};
        float4* mo = (float4*)(macc + (size_t)blockIdx.x * NH * DD);
        int h = tid >> 6, ln = tid & 63;
        #pragma unroll
        for (int j = 0; j < 3; ++j) mo[h * C4 + j * 64 + ln] = z;
        if (tid < NH) {
            float* mp = ml + (size_t)blockIdx.x * NH * 2;
            mp[tid * 2 + 0] = -3.0e38f; mp[tid * 2 + 1] = 0.f;
        }
        return;
    }

    float m0 = -3.0e38f, m1 = -3.0e38f, m2 = -3.0e38f, m3 = -3.0e38f;
    float l0 = 0.f, l1 = 0.f, l2 = 0.f, l3 = 0.f;
    float4 A00{0,0,0,0}, A01{0,0,0,0}, A02{0,0,0,0};
    float4 A10{0,0,0,0}, A11{0,0,0,0}, A12{0,0,0,0};
    float4 A20{0,0,0,0}, A21{0,0,0,0}, A22{0,0,0,0};
    float4 A30{0,0,0,0}, A31{0,0,0,0}, A32{0,0,0,0};

    const float* Hc = H + ((size_t)b * TT + t0) * DD;
    const int woff = wave * 1536;

    {
        float* dst = (float*)&Hts[0][0] + woff;
        const float* src = Hc + woff;
        #pragma unroll
        for (int i = 0; i < 6; ++i)
            gl_lds16(src + i * 256 + lane * 4, dst + i * 256);
    }

    #pragma unroll 1
    for (int t = 0; t < NTE; ++t) {
        const int cur = t & 1;
        if (t + 1 < NTE) {
            float* dst = (float*)&Hts[cur ^ 1][0] + woff;
            const float* src = Hc + (size_t)(t + 1) * TROWS * DD + woff;
            #pragma unroll
            for (int i = 0; i < 6; ++i)
                gl_lds16(src + i * 256 + lane * 4, dst + i * 256);
            WAITVM6();
        } else {
            WAITVM0();
        }
        const float4* Hr = &Hts[cur][0] + wave * 384;
        float4 c0 = Hr[lane],       c1 = Hr[64 + lane],  c2 = Hr[128 + lane];
        float4 c3 = Hr[192 + lane], c4 = Hr[256 + lane], c5 = Hr[320 + lane];

        float s00 = 0, s01 = 0, s02 = 0, s03 = 0;
        float s10 = 0, s11 = 0, s12 = 0, s13 = 0;
        DOT(s00, c0, qr[0][0]); DOT(s00, c1, qr[0][1]); DOT(s00, c2, qr[0][2]);
        DOT(s01, c0, qr[1][0]); DOT(s01, c1, qr[1][1]); DOT(s01, c2, qr[1][2]);
        DOT(s02, c0, qr[2][0]); DOT(s02, c1, qr[2][1]); DOT(s02, c2, qr[2][2]);
        DOT(s03, c0, qr[3][0]); DOT(s03, c1, qr[3][1]); DOT(s03, c2, qr[3][2]);
        DOT(s10, c3, qr[0][0]); DOT(s10, c4, qr[0][1]); DOT(s10, c5, qr[0][2]);
        DOT(s11, c3, qr[1][0]); DOT(s11, c4, qr[1][1]); DOT(s11, c5, qr[1][2]);
        DOT(s12, c3, qr[2][0]); DOT(s12, c4, qr[2][1]); DOT(s12, c5, qr[2][2]);
        DOT(s13, c3, qr[3][0]); DOT(s13, c4, qr[3][1]); DOT(s13, c5, qr[3][2]);
        float r00 = wave_sum64(s00), r01 = wave_sum64(s01);
        float r02 = wave_sum64(s02), r03 = wave_sum64(s03);
        float r10 = wave_sum64(s10), r11 = wave_sum64(s11);
        float r12 = wave_sum64(s12), r13 = wave_sum64(s13);
        float4 rb0 = rbL[t * TROWS + 2 * wave];
        float4 rb1 = rbL[t * TROWS + 2 * wave + 1];
        r00 += rb0.x; r01 += rb0.y; r02 += rb0.z; r03 += rb0.w;
        r10 += rb1.x; r11 += rb1.y; r12 += rb1.z; r13 += rb1.w;
        HUPD(m0, l0, r00, r10, A00, A01, A02);
        HUPD(m1, l1, r01, r11, A10, A11, A12);
        HUPD(m2, l2, r02, r12, A20, A21, A22);
        HUPD(m3, l3, r03, r13, A30, A31, A32);
    }

    // ---- in-block 4-wave flash combine (Hts reused as scratch) ----
    __syncthreads();
    float4* scr = (float4*)&Hts[0][0];
    #pragma unroll
    for (int j = 0; j < 3; ++j) {
        scr[(wave * 4 + 0) * C4 + j * 64 + lane] = j == 0 ? A00 : (j == 1 ? A01 : A02);
        scr[(wave * 4 + 1) * C4 + j * 64 + lane] = j == 0 ? A10 : (j == 1 ? A11 : A12);
        scr[(wave * 4 + 2) * C4 + j * 64 + lane] = j == 0 ? A20 : (j == 1 ? A21 : A22);
        scr[(wave * 4 + 3) * C4 + j * 64 + lane] = j == 0 ? A30 : (j == 1 ? A31 : A32);
    }
    if (lane == 0) {
        mls[wave][0] = m0; mls[wave][1] = l0; mls[wave][2] = m1; mls[wave][3] = l1;
        mls[wave][4] = m2; mls[wave][5] = l2; mls[wave][6] = m3; mls[wave][7] = l3;
    }
    __syncthreads();
    {
        int h = tid >> 6, ln = tid & 63;
        float M = fmaxf(fmaxf(mls[0][h*2], mls[1][h*2]), fmaxf(mls[2][h*2], mls[3][h*2]));
        float w0 = __expf(mls[0][h*2] - M), w1 = __expf(mls[1][h*2] - M);
        float w2 = __expf(mls[2][h*2] - M), w3 = __expf(mls[3][h*2] - M);
        float4* mo = (float4*)(macc + (size_t)blockIdx.x * NH * DD);
        #pragma unroll
        for (int j = 0; j < 3; ++j) {
            float4 v0 = scr[(0*4 + h) * C4 + j * 64 + ln];
            float4 v1 = scr[(1*4 + h) * C4 + j * 64 + ln];
            float4 v2 = scr[(2*4 + h) * C4 + j * 64 + ln];
            float4 v3 = scr[(3*4 + h) * C4 + j * 64 + ln];
            float4 v;
            v.x = w0*v0.x + w1*v1.x + w2*v2.x + w3*v3.x;
            v.y = w0*v0.y + w1*v1.y + w2*v2.y + w3*v3.y;
            v.z = w0*v0.z + w1*v1.z + w2*v2.z + w3*v3.z;
            v.w = w0*v0.w + w1*v1.w + w2*v2.w + w3*v3.w;
            mo[h * C4 + j * 64 + ln] = v;
        }
        if (tid < NH) {
            int hh = tid;
            float Mh = fmaxf(fmaxf(mls[0][hh*2], mls[1][hh*2]), fmaxf(mls[2][hh*2], mls[3][hh*2]));
            float Lh = __expf(mls[0][hh*2] - Mh) * mls[0][hh*2+1]
                     + __expf(mls[1][hh*2] - Mh) * mls[1][hh*2+1]
                     + __expf(mls[2][hh*2] - Mh) * mls[2][hh*2+1]
                     + __expf(mls[3][hh*2] - Mh) * mls[3][hh*2+1];
            float* mp = ml + (size_t)blockIdx.x * NH * 2;
            mp[hh * 2 + 0] = Mh; mp[hh * 2 + 1] = Lh;
        }
    }
}

// ---------------- kComb: hbar[b,h,d] = (1/L) * sum_ch w_ch * macc (128 blocks) ----------------
__global__ __launch_bounds__(256) void kComb(const float* __restrict__ macc,
                                             const float* __restrict__ ml,
                                             float* __restrict__ hbar) {
    int b = blockIdx.x / NH, h = blockIdx.x % NH;
    __shared__ float mlv[NCH][2];
    if (threadIdx.x < NCH) {
        const float* mp = ml + ((size_t)(b * NCH + threadIdx.x) * NH + h) * 2;
        mlv[threadIdx.x][0] = mp[0];
        mlv[threadIdx.x][1] = mp[1];
    }
    __syncthreads();
    float M = -3.0e38f;
    #pragma unroll
    for (int c = 0; c < NCH; ++c) M = fmaxf(M, mlv[c][0]);
    float L = 0.f;
    #pragma unroll
    for (int c = 0; c < NCH; ++c) L += __expf(mlv[c][0] - M) * mlv[c][1];
    float invL = 1.f / L;
    #pragma unroll
    for (int j = 0; j < 3; ++j) {
        int d = threadIdx.x + 256 * j;
        float acc = 0.f;
        const float* mc = macc + ((size_t)b * NCH * NH + h) * DD + d;
        #pragma unroll 8
        for (int c = 0; c < NCH; ++c)
            acc += __expf(mlv[c][0] - M) * mc[(size_t)c * NH * DD];
        hbar[((size_t)b * NH + h) * DD + d] = acc * invL;
    }
}

// ---------------- kTail: per b — WV proj + concat + GELU MLP (pw direct) + logits ----------------
__global__ __launch_bounds__(256) void kTail(const float* __restrict__ H,
                                             const int* __restrict__ noun_pos,
                                             const float* __restrict__ hbar,
                                             const float* __restrict__ WV,
                                             const float* __restrict__ pooled,
                                             const float* __restrict__ pw,
                                             const float* __restrict__ pb,
                                             const float* __restrict__ mw,
                                             const float* __restrict__ mb,
                                             float* __restrict__ out) {
    int b = blockIdx.x;
    int tid = threadIdx.x, wave = tid >> 6, lane = tid & 63;
    __shared__ float hb_s[NH * DD];   // 12 KB
    __shared__ float r_s[INPROJ];     // 7 KB
    __shared__ float hdn_s[HIDDEN];   // 1 KB

    int tn = noun_pos[b];
    const float* Hrow = H + ((size_t)b * TT + tn) * DD;
    for (int i = tid; i < NH * DD; i += 256) hb_s[i] = hbar[(size_t)b * NH * DD + i];
    for (int i = tid; i < DD; i += 256) {
        r_s[i] = Hrow[i];
        r_s[DD + NH * 64 + i] = pooled[(size_t)b * DD + i];
    }
    __syncthreads();
    {   // c[h,v] = hbar[h,:]·WV[h,:,v]
        int h = tid >> 6, v = tid & 63;
        const float* wv = WV + (size_t)h * DD * 64 + v;
        const float* hb = hb_s + h * DD;
        float acc = 0.f;
        #pragma unroll 8
        for (int d = 0; d < DD; ++d) acc += hb[d] * wv[(size_t)d * 64];
        r_s[DD + tid] = acc;
    }
    __syncthreads();
    {   // MLP: wave w owns rows j = jj*4 + w; lanes split i (coalesced pw reads)
        for (int jj = 0; jj < 64; ++jj) {
            int j = jj * 4 + wave;
            const float* pwr = pw + (size_t)j * INPROJ;
            float acc = 0.f;
            #pragma unroll
            for (int ii = 0; ii < INPROJ / 64; ++ii)
                acc += r_s[ii * 64 + lane] * pwr[ii * 64 + lane];
            float s = wave_sum64(acc);
            if (lane == 0) {
                s += pb[j];
                hdn_s[j] = 0.5f * s * (1.f + erff(s * 0.70710678118654752f));
            }
        }
    }
    __syncthreads();
    float p0 = hdn_s[tid] * mw[tid];
    float p1 = hdn_s[tid] * mw[HIDDEN + tid];
    #pragma unroll
    for (int off = 32; off; off >>= 1) {
        p0 += __shfl_xor(p0, off);
        p1 += __shfl_xor(p1, off);
    }
    __shared__ float r0[4], r1[4];
    if ((tid & 63) == 0) {
        r0[tid >> 6] = p0;
        r1[tid >> 6] = p1;
    }
    __syncthreads();
    if (tid == 0) {
        out[b * 2 + 0] = r0[0] + r0[1] + r0[2] + r0[3] + mb[0];
        out[b * 2 + 1] = r1[0] + r1[1] + r1[2] + r1[3] + mb[1];
    }
}

extern "C" void kernel_launch(void* const* d_in, const int* in_sizes, int n_in,
                              void* d_out, int out_size, void* d_ws, size_t ws_size,
                              hipStream_t stream) {
    const float* H      = (const float*)d_in[0];
    const int*   mask   = (const int*)d_in[1];
    const int*   noun   = (const int*)d_in[2];
    const float* pooled = (const float*)d_in[3];
    const float* WQ     = (const float*)d_in[4];
    const float* WK     = (const float*)d_in[5];
    const float* WV     = (const float*)d_in[6];
    const float* relb   = (const float*)d_in[7];
    const float* pw     = (const float*)d_in[8];
    const float* pb     = (const float*)d_in[9];
    const float* mw     = (const float*)d_in[10];
    const float* mb     = (const float*)d_in[11];
    float* out = (float*)d_out;

    float* ws   = (float*)d_ws;
    float* qk   = ws;                                 // BB*NH*DD      = 98304
    float* macc = qk + (size_t)BB * NH * DD;          // BB*NCH*NH*DD  = 3145728
    float* ml   = macc + (size_t)BB * NCH * NH * DD;  // BB*NCH*NH*2   = 8192
    float* hbar = ml + (size_t)BB * NCH * NH * 2;     // BB*NH*DD      = 98304

    kA<<<BB * NH, 256, 0, stream>>>(H, noun, WQ, WK, qk);
    kFlash<<<BB * NCH, 256, 0, stream>>>(H, mask, noun, relb, qk, macc, ml);
    kComb<<<BB * NH, 256, 0, stream>>>(macc, ml, hbar);
    kTail<<<BB, 256, 0, stream>>>(H, noun, hbar, WV, pooled, pw, pb, mw, mb, out);
}

// Round 13
// 151.169 us; speedup vs baseline: 1.1337x; 1.1337x over previous
//
#include <hip/hip_runtime.h>
#include <math.h>

#define BB 32
#define TT 4096
#define DD 768
#define NH 4
#define RELW 32
#define NREL 65
#define HIDDEN 256
#define INPROJ 1792  // DD + NH*64 + DD

#define NSTR 64      // strips per batch
#define SROWS 64     // rows per strip (1 wave, contiguous 192 KB stream)

// ---- wave64 sum via DPP (VALU pipe; validated R5/R9: absmax 0.0) ----
template <int CTRL, int RMASK>
__device__ __forceinline__ float upd0(float x) {
    return __int_as_float(__builtin_amdgcn_update_dpp(
        0, __float_as_int(x), CTRL, RMASK, 0xf, true));
}
__device__ __forceinline__ float wave_sum64(float x) {
    x += upd0<0x111, 0xf>(x);   // row_shr:1
    x += upd0<0x112, 0xf>(x);   // row_shr:2
    x += upd0<0x114, 0xf>(x);   // row_shr:4
    x += upd0<0x118, 0xf>(x);   // row_shr:8
    x += upd0<0x142, 0xa>(x);   // row_bcast:15
    x += upd0<0x143, 0xc>(x);   // row_bcast:31 -> lane63 = total
    return __int_as_float(__builtin_amdgcn_readlane(__float_as_int(x), 63));
}

// ---------------- kA: h_i -> R[:,0:768]; pooled -> R[:,1024:]; qk = (h_i WQ WK)/8 ----------------
__global__ __launch_bounds__(256) void kA(const float* __restrict__ H,
                                          const int* __restrict__ noun_pos,
                                          const float* __restrict__ WQ,
                                          const float* __restrict__ WK,
                                          const float* __restrict__ pooled,
                                          float* __restrict__ R,
                                          float* __restrict__ qk_ws) {
    int b = blockIdx.x / NH, h = blockIdx.x % NH;
    __shared__ float hi_s[DD];
    __shared__ float qpart[4][64];
    __shared__ float q_s[64];
    int tn = noun_pos[b];
    const float* Hrow = H + ((size_t)b * TT + tn) * DD;
    for (int d = threadIdx.x; d < DD; d += 256) {
        float v = Hrow[d];
        hi_s[d] = v;
        if (h == 0) R[(size_t)b * INPROJ + d] = v;
        if (h == 1) R[(size_t)b * INPROJ + DD + NH * 64 + d] = pooled[(size_t)b * DD + d];
    }
    __syncthreads();
    {   // q[k] = sum_d hi[d] * WQ[h,d,k] — 4-way d-split
        int k = threadIdx.x & 63, ds = threadIdx.x >> 6;
        const float* wq = WQ + (size_t)h * DD * 64 + k;
        float acc = 0.f;
        #pragma unroll 8
        for (int d = ds * 192; d < ds * 192 + 192; ++d) acc += hi_s[d] * wq[(size_t)d * 64];
        qpart[ds][k] = acc;
    }
    __syncthreads();
    if (threadIdx.x < 64)
        q_s[threadIdx.x] = qpart[0][threadIdx.x] + qpart[1][threadIdx.x]
                         + qpart[2][threadIdx.x] + qpart[3][threadIdx.x];
    __syncthreads();
    for (int d = threadIdx.x; d < DD; d += 256) {
        const float* wk = WK + ((size_t)h * DD + d) * 64;
        float acc = 0.f;
        #pragma unroll
        for (int k = 0; k < 64; ++k) acc += q_s[k] * wk[k];
        qk_ws[((size_t)b * NH + h) * DD + d] = acc * 0.125f;  // 1/sqrt(64)
    }
}

// ---------------- kFlashR: 1 wave / 64-row strip, contiguous stream, 2-deep reg pipeline ----------------
#define DOT(ACC, CV, QV) ACC += CV.x*QV.x + CV.y*QV.y + CV.z*QV.z + CV.w*QV.w

#define HUPD(M, L, S0, S1, B0, B1, B2)                                    \
  {                                                                        \
    float nm = fmaxf(M, fmaxf(S0, S1));                                    \
    if (nm > M + 8.0f) {                                                   \
      float sc = __expf(M - nm);                                           \
      L *= sc;                                                             \
      B0.x*=sc; B0.y*=sc; B0.z*=sc; B0.w*=sc;                              \
      B1.x*=sc; B1.y*=sc; B1.z*=sc; B1.w*=sc;                              \
      B2.x*=sc; B2.y*=sc; B2.z*=sc; B2.w*=sc;                              \
      M = nm;                                                              \
    }                                                                      \
    float p0 = __expf(S0 - M), p1 = __expf(S1 - M);                        \
    L += p0 + p1;                                                          \
    B0.x += p0*c0.x + p1*c3.x; B0.y += p0*c0.y + p1*c3.y;                  \
    B0.z += p0*c0.z + p1*c3.z; B0.w += p0*c0.w + p1*c3.w;                  \
    B1.x += p0*c1.x + p1*c4.x; B1.y += p0*c1.y + p1*c4.y;                  \
    B1.z += p0*c1.z + p1*c4.z; B1.w += p0*c1.w + p1*c4.w;                  \
    B2.x += p0*c2.x + p1*c5.x; B2.y += p0*c2.y + p1*c5.y;                  \
    B2.z += p0*c2.z + p1*c5.z; B2.w += p0*c2.w + p1*c5.w;                  \
  }

#define LOADSTEP(S, R0, R1, R2, R3, R4, R5)              \
  {                                                       \
    const float4* p_ = Hc + (size_t)(S) * 384;            \
    R0 = p_[lane];        R1 = p_[64 + lane];             \
    R2 = p_[128 + lane];  R3 = p_[192 + lane];            \
    R4 = p_[256 + lane];  R5 = p_[320 + lane];            \
  }

__global__ __launch_bounds__(64, 2) void kFlashR(const float* __restrict__ H,
                                                 const int* __restrict__ mask,
                                                 const int* __restrict__ noun_pos,
                                                 const float* __restrict__ rel_bias,
                                                 const float* __restrict__ qk_ws,
                                                 float* __restrict__ macc,
                                                 float* __restrict__ ml) {
    const int g = blockIdx.x;
    const int b = g >> 6, st = g & 63;
    const int lane = threadIdx.x;
    const int t0 = st * SROWS;
    const int tn = noun_pos[b];

    __shared__ float4 rbL[SROWS];   // 1 KB: mask-folded rel bias

    int t = t0 + lane;
    int dl = t - tn; dl = dl < -RELW ? -RELW : (dl > RELW ? RELW : dl);
    int mm = mask[(size_t)b * TT + t];
    {
        float4 rv;
        if (mm) {
            rv.x = rel_bias[0 * NREL + dl + RELW];
            rv.y = rel_bias[1 * NREL + dl + RELW];
            rv.z = rel_bias[2 * NREL + dl + RELW];
            rv.w = rel_bias[3 * NREL + dl + RELW];
        } else {
            rv.x = rv.y = rv.z = rv.w = -2.0e9f;
        }
        rbL[lane] = rv;
    }
    unsigned long long bal = __ballot(mm != 0);
    __syncthreads();

    if (bal == 0ull) {   // fully masked strip
        float4 z = {0.f, 0.f, 0.f, 0.f};
        float4* mo = (float4*)(macc + (size_t)g * NH * DD);
        #pragma unroll
        for (int j = 0; j < 12; ++j) mo[j * 64 + lane] = z;
        if (lane == 0) {
            float* mp = ml + (size_t)g * NH * 2;
            mp[0] = -3.0e38f; mp[1] = 0.f; mp[2] = -3.0e38f; mp[3] = 0.f;
            mp[4] = -3.0e38f; mp[5] = 0.f; mp[6] = -3.0e38f; mp[7] = 0.f;
        }
        return;
    }
    const int lastv = 63 - __builtin_clzll(bal);
    const int ns = (lastv + 2) >> 1;   // steps of 2 rows

    // qk fragments: head h, lane's 12 floats
    float4 qr[NH][3];
    {
        const float4* qk4 = (const float4*)(qk_ws + (size_t)b * NH * DD);
        #pragma unroll
        for (int h = 0; h < NH; ++h)
            #pragma unroll
            for (int j = 0; j < 3; ++j)
                qr[h][j] = qk4[h * 192 + j * 64 + lane];
    }

    float m0 = -3.0e38f, m1 = -3.0e38f, m2 = -3.0e38f, m3 = -3.0e38f;
    float l0 = 0.f, l1 = 0.f, l2 = 0.f, l3 = 0.f;
    float4 A00{0,0,0,0}, A01{0,0,0,0}, A02{0,0,0,0};
    float4 A10{0,0,0,0}, A11{0,0,0,0}, A12{0,0,0,0};
    float4 A20{0,0,0,0}, A21{0,0,0,0}, A22{0,0,0,0};
    float4 A30{0,0,0,0}, A31{0,0,0,0}, A32{0,0,0,0};

    const float4* __restrict__ Hc = (const float4*)(H + ((size_t)b * TT + t0) * DD);

    float4 z4 = {0.f,0.f,0.f,0.f};
    float4 c0, c1, c2, c3, c4, c5;
    float4 n0 = z4, n1 = z4, n2 = z4, n3 = z4, n4 = z4, n5 = z4;
    float4 o0 = z4, o1 = z4, o2 = z4, o3 = z4, o4 = z4, o5 = z4;

    LOADSTEP(0, c0, c1, c2, c3, c4, c5);
    if (1 < ns) LOADSTEP(1, n0, n1, n2, n3, n4, n5);

    #pragma unroll 1
    for (int s = 0; s < ns; ++s) {
        if (s + 2 < ns) LOADSTEP(s + 2, o0, o1, o2, o3, o4, o5);
        // in-lane partial dots: rows (c0..c2), (c3..c5) x 4 heads
        float s00 = 0, s01 = 0, s02 = 0, s03 = 0;
        float s10 = 0, s11 = 0, s12 = 0, s13 = 0;
        DOT(s00, c0, qr[0][0]); DOT(s00, c1, qr[0][1]); DOT(s00, c2, qr[0][2]);
        DOT(s01, c0, qr[1][0]); DOT(s01, c1, qr[1][1]); DOT(s01, c2, qr[1][2]);
        DOT(s02, c0, qr[2][0]); DOT(s02, c1, qr[2][1]); DOT(s02, c2, qr[2][2]);
        DOT(s03, c0, qr[3][0]); DOT(s03, c1, qr[3][1]); DOT(s03, c2, qr[3][2]);
        DOT(s10, c3, qr[0][0]); DOT(s10, c4, qr[0][1]); DOT(s10, c5, qr[0][2]);
        DOT(s11, c3, qr[1][0]); DOT(s11, c4, qr[1][1]); DOT(s11, c5, qr[1][2]);
        DOT(s12, c3, qr[2][0]); DOT(s12, c4, qr[2][1]); DOT(s12, c5, qr[2][2]);
        DOT(s13, c3, qr[3][0]); DOT(s13, c4, qr[3][1]); DOT(s13, c5, qr[3][2]);
        float r00 = wave_sum64(s00), r01 = wave_sum64(s01);
        float r02 = wave_sum64(s02), r03 = wave_sum64(s03);
        float r10 = wave_sum64(s10), r11 = wave_sum64(s11);
        float r12 = wave_sum64(s12), r13 = wave_sum64(s13);
        float4 rb0 = rbL[2 * s], rb1 = rbL[2 * s + 1];
        r00 += rb0.x; r01 += rb0.y; r02 += rb0.z; r03 += rb0.w;
        r10 += rb1.x; r11 += rb1.y; r12 += rb1.z; r13 += rb1.w;
        HUPD(m0, l0, r00, r10, A00, A01, A02);
        HUPD(m1, l1, r01, r11, A10, A11, A12);
        HUPD(m2, l2, r02, r12, A20, A21, A22);
        HUPD(m3, l3, r03, r13, A30, A31, A32);
        // rotate 2-deep pipeline
        c0 = n0; c1 = n1; c2 = n2; c3 = n3; c4 = n4; c5 = n5;
        n0 = o0; n1 = o1; n2 = o2; n3 = o3; n4 = o4; n5 = o5;
    }

    float4* mo = (float4*)(macc + (size_t)g * NH * DD);
    mo[0 * 192 + 0 * 64 + lane] = A00; mo[0 * 192 + 64 + lane] = A01; mo[0 * 192 + 128 + lane] = A02;
    mo[1 * 192 + 0 * 64 + lane] = A10; mo[1 * 192 + 64 + lane] = A11; mo[1 * 192 + 128 + lane] = A12;
    mo[2 * 192 + 0 * 64 + lane] = A20; mo[2 * 192 + 64 + lane] = A21; mo[2 * 192 + 128 + lane] = A22;
    mo[3 * 192 + 0 * 64 + lane] = A30; mo[3 * 192 + 64 + lane] = A31; mo[3 * 192 + 128 + lane] = A32;
    if (lane == 0) {
        float* mp = ml + (size_t)g * NH * 2;
        mp[0] = m0; mp[1] = l0; mp[2] = m1; mp[3] = l1;
        mp[4] = m2; mp[5] = l2; mp[6] = m3; mp[7] = l3;
    }
}

// ---------------- kT: transpose proj_w ----------------
__global__ __launch_bounds__(256) void kT(const float* __restrict__ pw,
                                          float* __restrict__ pwT) {
    int o = blockIdx.x * 256 + threadIdx.x;
    int j = o / INPROJ, i = o % INPROJ;
    pwT[(size_t)i * HIDDEN + j] = pw[o];
}

// ---------------- kComb: hbar = (1/L) * sum_strips w_c * macc (384 blocks) ----------------
__global__ __launch_bounds__(256) void kComb(const float* __restrict__ macc,
                                             const float* __restrict__ ml,
                                             float* __restrict__ hbar) {
    int blk = blockIdx.x;
    int b = blk / 12, rem = blk % 12, h = rem / 3, dseg = rem % 3;
    int d = dseg * 256 + threadIdx.x;
    const float* mlb = ml + (size_t)b * NSTR * 8 + h * 2;
    float M = -3.0e38f;
    #pragma unroll 8
    for (int c = 0; c < NSTR; ++c) M = fmaxf(M, mlb[(size_t)c * 8]);
    float L = 0.f;
    #pragma unroll 8
    for (int c = 0; c < NSTR; ++c)
        L += __expf(mlb[(size_t)c * 8] - M) * mlb[(size_t)c * 8 + 1];
    float acc = 0.f;
    const float* mc = macc + ((size_t)b * NSTR * NH + h) * DD + d;
    #pragma unroll 8
    for (int c = 0; c < NSTR; ++c)
        acc += __expf(mlb[(size_t)c * 8] - M) * mc[(size_t)c * NH * DD];
    hbar[((size_t)b * NH + h) * DD + d] = acc / L;
}

// ---------------- kC2: c = hbar*WV -> R[:,768:1024] ----------------
__global__ __launch_bounds__(256) void kC2(const float* __restrict__ hbar,
                                           const float* __restrict__ WV,
                                           float* __restrict__ R) {
    int b = blockIdx.x;
    int h = threadIdx.x >> 6, v = threadIdx.x & 63;
    const float* hb = hbar + ((size_t)b * NH + h) * DD;
    const float* wv = WV + (size_t)h * DD * 64 + v;
    float acc = 0.f;
    #pragma unroll 8
    for (int d = 0; d < DD; ++d) acc += hb[d] * wv[(size_t)d * 64];
    R[(size_t)b * INPROJ + DD + threadIdx.x] = acc;
}

// ---------------- kH1: partial hidden GEMM, 7-way split over INPROJ ----------------
__global__ __launch_bounds__(256) void kH1(const float* __restrict__ R,
                                           const float* __restrict__ pwT,
                                           float* __restrict__ part2) {
    int b = blockIdx.x / 7, seg = blockIdx.x % 7;
    int j = threadIdx.x;
    __shared__ float r_s[256];
    r_s[j] = R[(size_t)b * INPROJ + seg * 256 + j];
    __syncthreads();
    float acc = 0.f;
    const float* pT = pwT + (size_t)seg * 256 * HIDDEN + j;
    #pragma unroll 8
    for (int i = 0; i < 256; ++i) acc += r_s[i] * pT[(size_t)i * HIDDEN];
    part2[((size_t)b * 7 + seg) * HIDDEN + j] = acc;
}

// ---------------- kH2: reduce partials + GELU + logits ----------------
__global__ __launch_bounds__(256) void kH2(const float* __restrict__ part2,
                                           const float* __restrict__ pb,
                                           const float* __restrict__ mw,
                                           const float* __restrict__ mb,
                                           float* __restrict__ out) {
    int b = blockIdx.x, j = threadIdx.x;
    float acc = pb[j];
    #pragma unroll
    for (int s = 0; s < 7; ++s) acc += part2[((size_t)b * 7 + s) * HIDDEN + j];
    float hdn = 0.5f * acc * (1.f + erff(acc * 0.70710678118654752f));
    float p0 = hdn * mw[j];
    float p1 = hdn * mw[HIDDEN + j];
    #pragma unroll
    for (int off = 32; off; off >>= 1) {
        p0 += __shfl_xor(p0, off);
        p1 += __shfl_xor(p1, off);
    }
    __shared__ float r0[4], r1[4];
    if ((j & 63) == 0) {
        r0[j >> 6] = p0;
        r1[j >> 6] = p1;
    }
    __syncthreads();
    if (j == 0) {
        out[b * 2 + 0] = r0[0] + r0[1] + r0[2] + r0[3] + mb[0];
        out[b * 2 + 1] = r1[0] + r1[1] + r1[2] + r1[3] + mb[1];
    }
}

extern "C" void kernel_launch(void* const* d_in, const int* in_sizes, int n_in,
                              void* d_out, int out_size, void* d_ws, size_t ws_size,
                              hipStream_t stream) {
    const float* H      = (const float*)d_in[0];
    const int*   mask   = (const int*)d_in[1];
    const int*   noun   = (const int*)d_in[2];
    const float* pooled = (const float*)d_in[3];
    const float* WQ     = (const float*)d_in[4];
    const float* WK     = (const float*)d_in[5];
    const float* WV     = (const float*)d_in[6];
    const float* relb   = (const float*)d_in[7];
    const float* pw     = (const float*)d_in[8];
    const float* pb     = (const float*)d_in[9];
    const float* mw     = (const float*)d_in[10];
    const float* mb     = (const float*)d_in[11];
    float* out = (float*)d_out;

    float* ws    = (float*)d_ws;
    float* R     = ws;                                 // BB*INPROJ      = 57344
    float* qk    = R + (size_t)BB * INPROJ;            // BB*NH*DD       = 98304
    float* macc  = qk + (size_t)BB * NH * DD;          // BB*NSTR*NH*DD  = 6291456
    float* ml    = macc + (size_t)BB * NSTR * NH * DD; // BB*NSTR*NH*2   = 16384
    float* hbar  = ml + (size_t)BB * NSTR * NH * 2;    // BB*NH*DD       = 98304
    float* pwT   = hbar + (size_t)BB * NH * DD;        // INPROJ*HIDDEN  = 458752
    float* part2 = pwT + (size_t)INPROJ * HIDDEN;      // BB*7*HIDDEN    = 57344

    kA<<<BB * NH, 256, 0, stream>>>(H, noun, WQ, WK, pooled, R, qk);
    kT<<<(HIDDEN * INPROJ) / 256, 256, 0, stream>>>(pw, pwT);
    kFlashR<<<BB * NSTR, 64, 0, stream>>>(H, mask, noun, relb, qk, macc, ml);
    kComb<<<BB * 12, 256, 0, stream>>>(macc, ml, hbar);
    kC2<<<BB, 256, 0, stream>>>(hbar, WV, R);
    kH1<<<BB * 7, 256, 0, stream>>>(R, pwT, part2);
    kH2<<<BB, 256, 0, stream>>>(part2, pb, mw, mb, out);
}